// Round 14
// baseline (147.154 us; speedup 1.0000x reference)
//
#include <hip/hip_runtime.h>

// Problem constants (complete bipartite proxy<->sample + self-loops)
#define PP 100    // proxies
#define NS 1024   // samples
#define NN 1124   // total nodes
#define DD 512    // feature dim
#define CC 100    // fc out dim
#define NTHR 256  // prep kernels
#define GT  512   // GEMM kernels (8 waves: 4 row x 2 col of 16x32)

typedef _Float16 f16;
typedef _Float16 f16x8 __attribute__((ext_vector_type(8)));
typedef float    f32x4 __attribute__((ext_vector_type(4)));

__device__ __forceinline__ float lk(float v) { return v > 0.f ? v : 0.2f * v; }
__device__ __forceinline__ f16 hif(float v) { return (f16)v; }
__device__ __forceinline__ f16 lof(float v) { return (f16)(v - (float)((f16)v)); }

#define MFMA16(a, b, c) __builtin_amdgcn_mfma_f32_16x16x32_f16(a, b, c, 0, 0, 0)

// LDS (BK=128): rows of 136 halves (128 + 8 pad; row stride 272B -> 2-way
// bank aliasing only, free). Sections: Ash=0, Asl=8704, Bsh=17408,
// Bsl=26112; buffer 34816 halves; double-buffered = 69632 halves (136 KiB).
// 512-thread role split: t<256 stages A (row tt>>2, 32-half unit tt&3),
// t>=256 stages B. Waves: wr=w>>1 rows [wr*16..), wc=w&1 cols [wc*32..);
// per wave acc[2], 24 MFMA per K-step (four k-slices of 32).
#define LROW   136
#define SEC_AL 8704
#define SEC_BH 17408
#define SEC_BL 26112
#define BUFSZ  34816

// =================== MFMA split-f16 GEMM core (512 thr, BK=128) ============
__device__ __forceinline__ void mgemm_core(
    const f16* __restrict__ Ah, const f16* __restrict__ Al,
    const f16* __restrict__ Bth, const f16* __restrict__ Btl,
    int K, int row0, int col0, f16* __restrict__ lds, f32x4 acc[2])
{
  const int t = threadIdx.x;
  const int lane = t & 63, w = t >> 6;
  const int wr = w >> 1, wc = w & 1;
  const bool isA = t < 256;
  const int tt = t & 255;
  const int srow = tt >> 2, su = tt & 3;
  const int lw = srow * LROW + su * 32;
  const int sec0 = isA ? 0 : SEC_BH, sec1 = isA ? SEC_AL : SEC_BL;
  const f16* g0 = isA ? Ah : Bth;
  const f16* g1 = isA ? Al : Btl;
  const size_t goff = (size_t)((isA ? row0 : col0) + srow) * K + su * 32;
  const int fra = wr * 16 + (lane & 15);
  const int frb = wc * 32 + (lane & 15);
  const int fu  = (lane >> 4) * 8;
  f32x4 p[8];
  auto pf = [&](int k) {
#pragma unroll
    for (int i = 0; i < 4; ++i) {
      p[i]     = *(const f32x4*)(g0 + goff + k + i * 8);
      p[4 + i] = *(const f32x4*)(g1 + goff + k + i * 8);
    }
  };
  auto st = [&](f16* buf) {
#pragma unroll
    for (int i = 0; i < 4; ++i) {
      *(f32x4*)(buf + sec0 + lw + i * 8) = p[i];
      *(f32x4*)(buf + sec1 + lw + i * 8) = p[4 + i];
    }
  };
  pf(0); st(lds);
  if (K > 128) pf(128);
  __syncthreads();
  int cur = 0;
  for (int kt = 128; kt <= K; kt += 128) {
    f16* rb = lds + cur * BUFSZ;
    f16* wb = lds + (cur ^ 1) * BUFSZ;
    f16x8 ah[4], al[4], bh0[4], bl0[4], bh1[4], bl1[4];
#pragma unroll
    for (int s = 0; s < 4; ++s) {
      ah[s]  = *(const f16x8*)(rb + fra * LROW + s * 32 + fu);
      al[s]  = *(const f16x8*)(rb + SEC_AL + fra * LROW + s * 32 + fu);
      bh0[s] = *(const f16x8*)(rb + SEC_BH + frb * LROW + s * 32 + fu);
      bl0[s] = *(const f16x8*)(rb + SEC_BL + frb * LROW + s * 32 + fu);
      bh1[s] = *(const f16x8*)(rb + SEC_BH + (frb + 16) * LROW + s * 32 + fu);
      bl1[s] = *(const f16x8*)(rb + SEC_BL + (frb + 16) * LROW + s * 32 + fu);
    }
    if (kt < K) {
      st(wb);
      if (kt + 128 < K) pf(kt + 128);
    }
#pragma unroll
    for (int s = 0; s < 4; ++s) {
      acc[0] = MFMA16(ah[s], bh0[s], acc[0]);
      acc[0] = MFMA16(al[s], bh0[s], acc[0]);
      acc[0] = MFMA16(ah[s], bl0[s], acc[0]);
    }
#pragma unroll
    for (int s = 0; s < 4; ++s) {
      acc[1] = MFMA16(ah[s], bh1[s], acc[1]);
      acc[1] = MFMA16(al[s], bh1[s], acc[1]);
      acc[1] = MFMA16(ah[s], bl1[s], acc[1]);
    }
    __syncthreads();
    cur ^= 1;
  }
}

// ============ fused softmax+aggregation GEMM (short-K, 512 thr, BK=128) ====
__device__ __forceinline__ void agg_core(
    const float* __restrict__ lsrc, int kvalid,
    const float* __restrict__ ldb, const float* __restrict__ lsb,
    const f16* __restrict__ Bth, const f16* __restrict__ Btl,
    int K, int row0, int col0, int rvalid,
    const float* __restrict__ selfv,
    f16* __restrict__ outh, f16* __restrict__ outl,
    f16* __restrict__ lds, float* __restrict__ fred)
{
  const int t = threadIdx.x, lane = t & 63, w = t >> 6;
  const int wr = w >> 1, wc = w & 1;
  float* zred = fred;          // [256]
  float* res  = fred + 256;    // [64] self exps
  float* riz  = fred + 320;    // [64] 1/denominator
  float sm = -1e30f;
  for (int k = t; k < kvalid; k += GT) sm = fmaxf(sm, lsrc[k]);
#pragma unroll
  for (int off = 1; off < 64; off <<= 1) sm = fmaxf(sm, __shfl_xor(sm, off));
  if (lane == 0) zred[w] = sm;
  __syncthreads();
  sm = fmaxf(fmaxf(fmaxf(zred[0], zred[1]), fmaxf(zred[2], zred[3])),
             fmaxf(fmaxf(zred[4], zred[5]), fmaxf(zred[6], zred[7])));
  __syncthreads();
  const bool isA = t < 256;
  const int tt = t & 255;
  const int srow = tt >> 2, su = tt & 3;
  const int lw = srow * LROW + su * 32;
  bool rok = false; float ldr = 0.f, mr = 0.f;
  if (isA && (row0 + srow) < rvalid) {
    rok = true;
    ldr = ldb[row0 + srow];
    mr  = lk(fmaxf(sm, lsb[row0 + srow]) + ldr);
  }
  const size_t boff = (size_t)(col0 + srow) * K + su * 32;
  const int fra = wr * 16 + (lane & 15);
  const int frb = wc * 32 + (lane & 15);
  const int fu  = (lane >> 4) * 8;
  f32x4 acc[2] = {};
  float zacc = 0.f;
  f32x4 p[8];
  auto prefetch = [&](int k) {
    if (isA) {
#pragma unroll
      for (int i = 0; i < 8; ++i)
        p[i] = *(const f32x4*)(lsrc + k + su * 32 + i * 4);
    } else {
#pragma unroll
      for (int i = 0; i < 4; ++i) {
        p[i]     = *(const f32x4*)(Bth + boff + k + i * 8);
        p[4 + i] = *(const f32x4*)(Btl + boff + k + i * 8);
      }
    }
  };
  auto stage = [&](f16* buf, int kbase) {
    if (isA) {
#pragma unroll
      for (int g = 0; g < 2; ++g) {
        f16x8 h0, h1v, l0, l1v;
#pragma unroll
        for (int j = 0; j < 16; ++j) {
          const int k = kbase + su * 32 + g * 16 + j;
          const float lv = p[g * 4 + (j >> 2)][j & 3];
          float f = 0.f;
          if (rok && k < kvalid) f = __expf(lk(lv + ldr) - mr);
          zacc += f;
          if (j < 8) { h0[j] = hif(f); l0[j] = lof(f); }
          else       { h1v[j - 8] = hif(f); l1v[j - 8] = lof(f); }
        }
        *(f16x8*)(buf + lw + g * 16)              = h0;
        *(f16x8*)(buf + lw + g * 16 + 8)          = h1v;
        *(f16x8*)(buf + SEC_AL + lw + g * 16)     = l0;
        *(f16x8*)(buf + SEC_AL + lw + g * 16 + 8) = l1v;
      }
    } else {
#pragma unroll
      for (int i = 0; i < 4; ++i) {
        *(f32x4*)(buf + SEC_BH + lw + i * 8) = p[i];
        *(f32x4*)(buf + SEC_BL + lw + i * 8) = p[4 + i];
      }
    }
  };
  prefetch(0);
  stage(lds, 0);
  if (K > 128) prefetch(128);
  __syncthreads();
  int cur = 0;
  for (int kt = 128; kt <= K; kt += 128) {
    f16* rb = lds + cur * BUFSZ;
    f16* wb = lds + (cur ^ 1) * BUFSZ;
    f16x8 ah[4], al[4], bh0[4], bl0[4], bh1[4], bl1[4];
#pragma unroll
    for (int s = 0; s < 4; ++s) {
      ah[s]  = *(const f16x8*)(rb + fra * LROW + s * 32 + fu);
      al[s]  = *(const f16x8*)(rb + SEC_AL + fra * LROW + s * 32 + fu);
      bh0[s] = *(const f16x8*)(rb + SEC_BH + frb * LROW + s * 32 + fu);
      bl0[s] = *(const f16x8*)(rb + SEC_BL + frb * LROW + s * 32 + fu);
      bh1[s] = *(const f16x8*)(rb + SEC_BH + (frb + 16) * LROW + s * 32 + fu);
      bl1[s] = *(const f16x8*)(rb + SEC_BL + (frb + 16) * LROW + s * 32 + fu);
    }
    if (kt < K) {
      stage(wb, kt);
      if (kt + 128 < K) prefetch(kt + 128);
    }
#pragma unroll
    for (int s = 0; s < 4; ++s) {
      acc[0] = MFMA16(ah[s], bh0[s], acc[0]);
      acc[0] = MFMA16(al[s], bh0[s], acc[0]);
      acc[0] = MFMA16(ah[s], bl0[s], acc[0]);
    }
#pragma unroll
    for (int s = 0; s < 4; ++s) {
      acc[1] = MFMA16(ah[s], bh1[s], acc[1]);
      acc[1] = MFMA16(al[s], bh1[s], acc[1]);
      acc[1] = MFMA16(ah[s], bl1[s], acc[1]);
    }
    __syncthreads();
    cur ^= 1;
  }
  if (t < 256) zred[t] = zacc;
  __syncthreads();
  if (t < 64) {
    float z = zred[t * 4] + zred[t * 4 + 1] + zred[t * 4 + 2] + zred[t * 4 + 3];
    float es = 0.f, iz = 0.f;
    if (row0 + t < rvalid) {
      const float l2 = ldb[row0 + t], s2 = lsb[row0 + t];
      const float m2 = lk(fmaxf(sm, s2) + l2);
      es = __expf(lk(s2 + l2) - m2);
      iz = 1.f / (z + es);
    }
    res[t] = es; riz[t] = iz;
  }
  __syncthreads();
#pragma unroll
  for (int q = 0; q < 4; ++q) {
    const int rl = wr * 16 + (lane >> 4) * 4 + q;
    const int gr = row0 + rl;
    if (gr >= rvalid) continue;
    const float es = res[rl], iz = riz[rl];
#pragma unroll
    for (int n = 0; n < 2; ++n) {
      const int c = col0 + wc * 32 + n * 16 + (lane & 15);
      const float v = (acc[n][q] + es * selfv[(size_t)gr * DD + c]) * iz;
      outh[(size_t)gr * DD + c] = hif(v);
      outl[(size_t)gr * DD + c] = lof(v);
    }
  }
}

// ======== 64x64 direct transpose+split tile (no LDS, one pass) =============
__device__ __forceinline__ void cvt_tile(
    const float* __restrict__ in, int R, int Cin,
    f16* __restrict__ oh, f16* __restrict__ ol, int ldo,
    int ti, int tj)
{
  const int t = threadIdx.x;
  const int gj0 = tj * 64 + (t & 31) * 2;
  const int i8  = (t >> 5) * 8;
  const bool c0 = gj0 < Cin, c1 = (gj0 + 1) < Cin;
  f16x8 vh0, vl0, vh1, vl1;
#pragma unroll
  for (int e = 0; e < 8; ++e) {
    const int gi = ti * 64 + i8 + e;
    float a = 0.f, b = 0.f;
    if (gi < R) {
      if (c0 && c1) {
        const float2 v = *(const float2*)(in + (size_t)gi * Cin + gj0);
        a = v.x; b = v.y;
      } else if (c0) {
        a = in[(size_t)gi * Cin + gj0];
      }
    }
    vh0[e] = hif(a); vl0[e] = lof(a);
    vh1[e] = hif(b); vl1[e] = lof(b);
  }
  const size_t o0 = (size_t)gj0 * ldo + ti * 64 + i8;
  *(f16x8*)(oh + o0) = vh0;
  *(f16x8*)(ol + o0) = vl0;
  const size_t o1 = o0 + ldo;
  *(f16x8*)(oh + o1) = vh1;
  *(f16x8*)(ol + o1) = vl1;
}

// ===== K1: weight matvecs + zero ls2/ld2 + zero M1pf/zP ====================
__global__ __launch_bounds__(NTHR) void prep1_k(
    const float* __restrict__ W1, const float* __restrict__ W2,
    const float* __restrict__ as1, const float* __restrict__ ad1,
    const float* __restrict__ as2, const float* __restrict__ ad2,
    float* __restrict__ v1s, float* __restrict__ v1d,
    float* __restrict__ v2s, float* __restrict__ v2d,
    float* __restrict__ ls2, float* __restrict__ ld2,
    float* __restrict__ M1pf, float* __restrict__ zP)
{
  const int u = blockIdx.x;
  if (u < 256) {
    const int wid  = u * 4 + (threadIdx.x >> 6);
    const int lane = threadIdx.x & 63;
    const int r = wid & 511;
    const bool l1 = (wid < 512);
    const float* W = l1 ? W1 : W2;
    const float4* a4 = (const float4*)(l1 ? as1 : as2);
    const float4* b4 = (const float4*)(l1 ? ad1 : ad2);
    const float4* w4 = (const float4*)(W + (size_t)r * DD);
    float4 w0 = w4[lane], w1 = w4[lane + 64];
    float4 a0 = a4[lane], a1 = a4[lane + 64];
    float4 b0 = b4[lane], b1 = b4[lane + 64];
    float s1 = w0.x * a0.x + w0.y * a0.y + w0.z * a0.z + w0.w * a0.w
             + w1.x * a1.x + w1.y * a1.y + w1.z * a1.z + w1.w * a1.w;
    float s2 = w0.x * b0.x + w0.y * b0.y + w0.z * b0.z + w0.w * b0.w
             + w1.x * b1.x + w1.y * b1.y + w1.z * b1.z + w1.w * b1.w;
#pragma unroll
    for (int off = 32; off > 0; off >>= 1) {
      s1 += __shfl_down(s1, off);
      s2 += __shfl_down(s2, off);
    }
    if (lane == 0) {
      (l1 ? v1s : v2s)[r] = s1;
      (l1 ? v1d : v2d)[r] = s2;
    }
  } else if (u == 256) {
    for (int i = threadIdx.x; i < 1152; i += NTHR) { ls2[i] = 0.f; ld2[i] = 0.f; }
    if (threadIdx.x < 128) zP[threadIdx.x] = 0.f;
  } else {
    float4* p4 = (float4*)M1pf + (size_t)(u - 257) * 800;
#pragma unroll
    for (int p = 0; p < 4; ++p) {
      const int i = threadIdx.x + p * 256;
      if (i < 800) p4[i] = make_float4(0.f, 0.f, 0.f, 0.f);
    }
  }
}

// ===== K2: transposes/splits + layer-1 logits ==============================
__global__ __launch_bounds__(NTHR) void prep2_k(
    const float* __restrict__ x, const float* __restrict__ prox,
    const float* __restrict__ W1, const float* __restrict__ W2,
    const float* __restrict__ fcw,
    const float* __restrict__ v1s, const float* __restrict__ v1d,
    f16* xth, f16* xtl, f16* pth, f16* ptl,
    f16* W1th, f16* W1tl, f16* W2th, f16* W2tl, f16* fwth, f16* fwtl,
    float* __restrict__ ls1, float* __restrict__ ld1)
{
  const int b = blockIdx.x;
  if (b < 64) {
    cvt_tile(W1, 512, 512, W1th, W1tl, 512, b >> 3, b & 7);
  } else if (b < 128) {
    cvt_tile(W2, 512, 512, W2th, W2tl, 512, (b - 64) >> 3, (b - 64) & 7);
  } else if (b < 256) {
    cvt_tile(x, NS, 512, xth, xtl, NS, (b - 128) >> 3, (b - 128) & 7);
  } else if (b < 272) {
    cvt_tile(prox, PP, 512, pth, ptl, 128, (b - 256) >> 3, (b - 256) & 7);
  } else if (b < 288) {
    cvt_tile(fcw, 512, CC, fwth, fwtl, 512, (b - 272) >> 1, (b - 272) & 1);
  } else {
    const int r    = (b - 288) * 4 + (threadIdx.x >> 6);
    const int lane = threadIdx.x & 63;
    if (r >= NN) return;
    const float* row = (r < PP) ? prox + (size_t)r * DD
                                : x + (size_t)(r - PP) * DD;
    const float4* r4 = (const float4*)row;
    const float4* s4 = (const float4*)v1s;
    const float4* d4 = (const float4*)v1d;
    float4 v0 = r4[lane], v1 = r4[lane + 64];
    float4 a0 = s4[lane], a1 = s4[lane + 64];
    float4 b0 = d4[lane], b1 = d4[lane + 64];
    float s1 = v0.x * a0.x + v0.y * a0.y + v0.z * a0.z + v0.w * a0.w
             + v1.x * a1.x + v1.y * a1.y + v1.z * a1.z + v1.w * a1.w;
    float s2 = v0.x * b0.x + v0.y * b0.y + v0.z * b0.z + v0.w * b0.w
             + v1.x * b1.x + v1.y * b1.y + v1.z * b1.z + v1.w * b1.w;
#pragma unroll
    for (int off = 32; off > 0; off >>= 1) {
      s1 += __shfl_down(s1, off);
      s2 += __shfl_down(s2, off);
    }
    if (lane == 0) { ls1[r] = s1; ld1[r] = s2; }
  }
}

// ===== K3: layer-1 aggregation (512 thr, BK=128) ===========================
// blocks [0,128): sample dsts (fused softmax, K=128)
// blocks [128,192): proxy split-K partials (16 tiles x 4 chunks of 256)
__global__ __launch_bounds__(GT) void agg1x_k(
    const float* __restrict__ ls1, const float* __restrict__ ld1,
    const f16* __restrict__ pth, const f16* __restrict__ ptl,
    const f16* __restrict__ xth, const f16* __restrict__ xtl,
    const float* __restrict__ x,
    float* __restrict__ M1pf, float* __restrict__ zP,
    f16* __restrict__ M1h, f16* __restrict__ M1l)
{
  __shared__ __align__(16) f16 lds[69632];
  __shared__ float fred[384];
  const int b = blockIdx.x;
  if (b < 128) {
    const int row0 = (b >> 3) * 64, col0 = (b & 7) * 64;
    agg_core(ls1, PP, ld1 + PP, ls1 + PP, pth, ptl, 128, row0, col0, NS,
             x, M1h + (size_t)PP * DD, M1l + (size_t)PP * DD, lds, fred);
    return;
  }
  // ---- proxy split-K partial ----
  const int t = threadIdx.x, lane = t & 63, w = t >> 6;
  const int wr = w >> 1, wc = w & 1;
  const int b2 = b - 128;
  const int tile = b2 >> 2, chunk = b2 & 3;
  const int row0 = (tile >> 3) * 64, col0 = (tile & 7) * 64;
  const int k0 = chunk * 256;
  const float* lsrc = ls1 + PP;
  float sm = -1e30f;
  for (int k = t; k < NS; k += GT) sm = fmaxf(sm, lsrc[k]);
#pragma unroll
  for (int off = 1; off < 64; off <<= 1) sm = fmaxf(sm, __shfl_xor(sm, off));
  if (lane == 0) fred[w] = sm;
  __syncthreads();
  sm = fmaxf(fmaxf(fmaxf(fred[0], fred[1]), fmaxf(fred[2], fred[3])),
             fmaxf(fmaxf(fred[4], fred[5]), fmaxf(fred[6], fred[7])));
  __syncthreads();
  const bool isA = t < 256;
  const int tt = t & 255;
  const int srow = tt >> 2, su = tt & 3;
  const int lw = srow * LROW + su * 32;
  bool rok = false; float ldr = 0.f, mr = 0.f;
  if (isA && (row0 + srow) < PP) {
    rok = true;
    ldr = ld1[row0 + srow];
    mr  = lk(fmaxf(sm, ls1[row0 + srow]) + ldr);
  }
  const size_t boff = (size_t)(col0 + srow) * NS + k0 + su * 32;
  const int fra = wr * 16 + (lane & 15);
  const int frb = wc * 32 + (lane & 15);
  const int fu  = (lane >> 4) * 8;
  f32x4 acc[2] = {};
  float zacc = 0.f;
  f32x4 p[8];
  auto prefetch = [&](int k) {
    if (isA) {
#pragma unroll
      for (int i = 0; i < 8; ++i)
        p[i] = *(const f32x4*)(lsrc + k0 + k + su * 32 + i * 4);
    } else {
#pragma unroll
      for (int i = 0; i < 4; ++i) {
        p[i]     = *(const f32x4*)(xth + boff + k + i * 8);
        p[4 + i] = *(const f32x4*)(xtl + boff + k + i * 8);
      }
    }
  };
  auto stage = [&](f16* buf) {
    if (isA) {
#pragma unroll
      for (int g = 0; g < 2; ++g) {
        f16x8 h0, h1v, l0, l1v;
#pragma unroll
        for (int j = 0; j < 16; ++j) {
          const float lv = p[g * 4 + (j >> 2)][j & 3];
          float f = 0.f;
          if (rok) f = __expf(lk(lv + ldr) - mr);
          zacc += f;
          if (j < 8) { h0[j] = hif(f); l0[j] = lof(f); }
          else       { h1v[j - 8] = hif(f); l1v[j - 8] = lof(f); }
        }
        *(f16x8*)(buf + lw + g * 16)              = h0;
        *(f16x8*)(buf + lw + g * 16 + 8)          = h1v;
        *(f16x8*)(buf + SEC_AL + lw + g * 16)     = l0;
        *(f16x8*)(buf + SEC_AL + lw + g * 16 + 8) = l1v;
      }
    } else {
#pragma unroll
      for (int i = 0; i < 4; ++i) {
        *(f32x4*)(buf + SEC_BH + lw + i * 8) = p[i];
        *(f32x4*)(buf + SEC_BL + lw + i * 8) = p[4 + i];
      }
    }
  };
  prefetch(0);
  stage(lds);
  prefetch(128);
  __syncthreads();
  int cur = 0;
  for (int kt = 128; kt <= 256; kt += 128) {
    f16* rb = lds + cur * BUFSZ;
    f16* wb = lds + (cur ^ 1) * BUFSZ;
    f16x8 ah[4], al[4], bh0[4], bl0[4], bh1[4], bl1[4];
#pragma unroll
    for (int s = 0; s < 4; ++s) {
      ah[s]  = *(const f16x8*)(rb + fra * LROW + s * 32 + fu);
      al[s]  = *(const f16x8*)(rb + SEC_AL + fra * LROW + s * 32 + fu);
      bh0[s] = *(const f16x8*)(rb + SEC_BH + frb * LROW + s * 32 + fu);
      bl0[s] = *(const f16x8*)(rb + SEC_BL + frb * LROW + s * 32 + fu);
      bh1[s] = *(const f16x8*)(rb + SEC_BH + (frb + 16) * LROW + s * 32 + fu);
      bl1[s] = *(const f16x8*)(rb + SEC_BL + (frb + 16) * LROW + s * 32 + fu);
    }
    if (kt < 256) stage(wb);
#pragma unroll
    for (int s = 0; s < 4; ++s) {
      acc[0] = MFMA16(ah[s], bh0[s], acc[0]);
      acc[0] = MFMA16(al[s], bh0[s], acc[0]);
      acc[0] = MFMA16(ah[s], bl0[s], acc[0]);
    }
#pragma unroll
    for (int s = 0; s < 4; ++s) {
      acc[1] = MFMA16(ah[s], bh1[s], acc[1]);
      acc[1] = MFMA16(al[s], bh1[s], acc[1]);
      acc[1] = MFMA16(ah[s], bl1[s], acc[1]);
    }
    __syncthreads();
    cur ^= 1;
  }
  // z depends only on (row, chunk) — add exactly once per chunk: col0==0 only
  if (col0 == 0) {
    if (t < 256) fred[t] = zacc;
    __syncthreads();
    if (t < 64) {
      const int r = row0 + t;
      if (r < PP) {
        float z = fred[t * 4] + fred[t * 4 + 1] + fred[t * 4 + 2] + fred[t * 4 + 3];
        atomicAdd(&zP[r], z);
      }
    }
  }
#pragma unroll
  for (int q = 0; q < 4; ++q) {
    const int gr = row0 + wr * 16 + (lane >> 4) * 4 + q;
    if (gr >= PP) continue;
#pragma unroll
    for (int n = 0; n < 2; ++n) {
      const int c = col0 + wc * 32 + n * 16 + (lane & 15);
      atomicAdd(&M1pf[(size_t)gr * DD + c], acc[n][q]);
    }
  }
}

// ===== K4: h1 = relu(M1@W1 + b1) (512 thr, BK=128); proxy finalize inline;
//           emit proxy^T splits; atomic layer-2 logits =====================
__global__ __launch_bounds__(GT) void h1_k(
    const f16* __restrict__ M1h, const f16* __restrict__ M1l,
    const float* __restrict__ M1pf, const float* __restrict__ zP,
    const float* __restrict__ ls1, const float* __restrict__ ld1,
    const float* __restrict__ prox,
    const f16* __restrict__ W1th, const f16* __restrict__ W1tl,
    const float* __restrict__ b1,
    const float* __restrict__ v2s, const float* __restrict__ v2d,
    float* __restrict__ h1, f16* __restrict__ h1pth, f16* __restrict__ h1ptl,
    float* __restrict__ ls2, float* __restrict__ ld2)
{
  __shared__ __align__(16) f16 lds[69632];
  __shared__ float fred[384];
  float* esA = fred + 256;   // [64]
  float* izA = fred + 320;   // [64]
  const int t = threadIdx.x, lane = t & 63, w = t >> 6;
  const int wr = w >> 1, wc = w & 1;
  const int b = blockIdx.x;
  const int row0 = (b >> 3) * 64, col0 = (b & 7) * 64;
  const bool hasP = (row0 < 128);
  if (hasP) {
    float sm = -1e30f;
    for (int k = t; k < NS; k += GT) sm = fmaxf(sm, ls1[PP + k]);
#pragma unroll
    for (int off = 1; off < 64; off <<= 1) sm = fmaxf(sm, __shfl_xor(sm, off));
    if (lane == 0) fred[w] = sm;
    __syncthreads();
    sm = fmaxf(fmaxf(fmaxf(fred[0], fred[1]), fmaxf(fred[2], fred[3])),
               fmaxf(fmaxf(fred[4], fred[5]), fmaxf(fred[6], fred[7])));
    if (t < 64) {
      const int r = row0 + t;
      float es = 0.f, iz = 0.f;
      if (r < PP) {
        const float ldr = ld1[r];
        const float m = lk(fmaxf(sm, ls1[r]) + ldr);
        es = __expf(lk(ls1[r] + ldr) - m);
        iz = 1.f / (zP[r] + es);
      }
      esA[t] = es; izA[t] = iz;
    }
    __syncthreads();
  }
  // ---- GEMM with role-split staging (A: mixed-source, B: W1 splits) ----
  const bool isA = t < 256;
  const int tt = t & 255;
  const int srow = tt >> 2, su = tt & 3;
  const int lw = srow * LROW + su * 32;
  const int ar = row0 + srow;
  const bool isP = isA && (ar < PP);
  const size_t aoff = (size_t)ar * DD + su * 32;
  const size_t boff = (size_t)(col0 + srow) * DD + su * 32;
  const int fra = wr * 16 + (lane & 15);
  const int frb = wc * 32 + (lane & 15);
  const int fu  = (lane >> 4) * 8;
  const float esr = isP ? esA[srow] : 0.f;
  const float izr = isP ? izA[srow] : 0.f;
  f32x4 qa[8], qb[8];
  auto loadS = [&](int k) {
    if (isA) {
      if (isP) {
#pragma unroll
        for (int i = 0; i < 8; ++i) {
          qa[i] = *(const f32x4*)(M1pf + aoff + k + i * 4);
          qb[i] = *(const f32x4*)(prox + aoff + k + i * 4);
        }
      } else {
#pragma unroll
        for (int i = 0; i < 4; ++i) {
          qa[i]     = *(const f32x4*)(M1h + aoff + k + i * 8);
          qa[4 + i] = *(const f32x4*)(M1l + aoff + k + i * 8);
        }
      }
    } else {
#pragma unroll
      for (int i = 0; i < 4; ++i) {
        qa[i]     = *(const f32x4*)(W1th + boff + k + i * 8);
        qa[4 + i] = *(const f32x4*)(W1tl + boff + k + i * 8);
      }
    }
  };
  auto storeS = [&](f16* wb) {
    if (isA) {
      if (isP) {
#pragma unroll
        for (int g = 0; g < 2; ++g) {
          f16x8 h0, h1v, l0, l1v;
#pragma unroll
          for (int j = 0; j < 16; ++j) {
            const float pv = qa[g * 4 + (j >> 2)][j & 3];
            const float xv = qb[g * 4 + (j >> 2)][j & 3];
            const float v = (pv + esr * xv) * izr;
            if (j < 8) { h0[j] = hif(v); l0[j] = lof(v); }
            else       { h1v[j - 8] = hif(v); l1v[j - 8] = lof(v); }
          }
          *(f16x8*)(wb + lw + g * 16)              = h0;
          *(f16x8*)(wb + lw + g * 16 + 8)          = h1v;
          *(f16x8*)(wb + SEC_AL + lw + g * 16)     = l0;
          *(f16x8*)(wb + SEC_AL + lw + g * 16 + 8) = l1v;
        }
      } else {
#pragma unroll
        for (int i = 0; i < 4; ++i) {
          *(f32x4*)(wb + lw + i * 8)          = qa[i];
          *(f32x4*)(wb + SEC_AL + lw + i * 8) = qa[4 + i];
        }
      }
    } else {
#pragma unroll
      for (int i = 0; i < 4; ++i) {
        *(f32x4*)(wb + SEC_BH + lw + i * 8) = qa[i];
        *(f32x4*)(wb + SEC_BL + lw + i * 8) = qa[4 + i];
      }
    }
  };
  f32x4 acc[2] = {};
  loadS(0);
  storeS(lds);
  loadS(128);
  __syncthreads();
  int cur = 0;
  for (int kt = 128; kt <= DD; kt += 128) {
    f16* rb = lds + cur * BUFSZ;
    f16* wb = lds + (cur ^ 1) * BUFSZ;
    f16x8 ah[4], al[4], bh0[4], bl0[4], bh1[4], bl1[4];
#pragma unroll
    for (int s = 0; s < 4; ++s) {
      ah[s]  = *(const f16x8*)(rb + fra * LROW + s * 32 + fu);
      al[s]  = *(const f16x8*)(rb + SEC_AL + fra * LROW + s * 32 + fu);
      bh0[s] = *(const f16x8*)(rb + SEC_BH + frb * LROW + s * 32 + fu);
      bl0[s] = *(const f16x8*)(rb + SEC_BL + frb * LROW + s * 32 + fu);
      bh1[s] = *(const f16x8*)(rb + SEC_BH + (frb + 16) * LROW + s * 32 + fu);
      bl1[s] = *(const f16x8*)(rb + SEC_BL + (frb + 16) * LROW + s * 32 + fu);
    }
    if (kt < DD) {
      storeS(wb);
      if (kt + 128 < DD) loadS(kt + 128);
    }
#pragma unroll
    for (int s = 0; s < 4; ++s) {
      acc[0] = MFMA16(ah[s], bh0[s], acc[0]);
      acc[0] = MFMA16(al[s], bh0[s], acc[0]);
      acc[0] = MFMA16(ah[s], bl0[s], acc[0]);
    }
#pragma unroll
    for (int s = 0; s < 4; ++s) {
      acc[1] = MFMA16(ah[s], bh1[s], acc[1]);
      acc[1] = MFMA16(al[s], bh1[s], acc[1]);
      acc[1] = MFMA16(ah[s], bl1[s], acc[1]);
    }
    __syncthreads();
    cur ^= 1;
  }
  // ---- epilogue ----
  const int c0 = col0 + wc * 32 + (lane & 15);
  const int c1 = c0 + 16;
  const float vs0 = v2s[c0], vs1 = v2s[c1];
  const float vd0 = v2d[c0], vd1 = v2d[c1];
  const float bb0 = b1[c0],  bb1 = b1[c1];
#pragma unroll
  for (int q = 0; q < 4; ++q) {
    const int r = row0 + wr * 16 + (lane >> 4) * 4 + q;
    if (r >= NN) continue;
    float ps = 0.f, pd = 0.f;
#pragma unroll
    for (int n = 0; n < 2; ++n) {
      const int c = (n == 0) ? c0 : c1;
      const float v = fmaxf(acc[n][q] + (n == 0 ? bb0 : bb1), 0.f);
      h1[(size_t)r * DD + c] = v;
      ps += v * (n == 0 ? vs0 : vs1);
      pd += v * (n == 0 ? vd0 : vd1);
      if (r < 128) {
        const size_t o = (size_t)c * 128 + r;
        f16 hh = (f16)0.f, ll = (f16)0.f;
        if (r < PP) { hh = hif(v); ll = lof(v); }
        h1pth[o] = hh; h1ptl[o] = ll;
      }
    }
#pragma unroll
    for (int off = 1; off < 16; off <<= 1) {
      ps += __shfl_xor(ps, off);
      pd += __shfl_xor(pd, off);
    }
    if ((lane & 15) == 0) {
      atomicAdd(&ls2[r], ps);
      atomicAdd(&ld2[r], pd);
    }
  }
}

// ===== K5: layer-2 aggregation (softmax fused; sample dsts only) ===========
__global__ __launch_bounds__(GT) void agg2x_k(
    const float* __restrict__ ls2, const float* __restrict__ ld2,
    const f16* __restrict__ h1pth, const f16* __restrict__ h1ptl,
    const float* __restrict__ h1,
    f16* __restrict__ M2h, f16* __restrict__ M2l)
{
  __shared__ __align__(16) f16 lds[69632];
  __shared__ float fred[384];
  const int b = blockIdx.x;
  const int row0 = (b >> 3) * 64, col0 = (b & 7) * 64;
  agg_core(ls2, PP, ld2 + PP, ls2 + PP, h1pth, h1ptl, 128, row0, col0, NS,
           h1 + (size_t)PP * DD, M2h, M2l, lds, fred);
}

// ===== K6: h2 = relu(M2@W2 + b2) -> d_out (fp32 only) ======================
__global__ __launch_bounds__(GT) void h2_k(
    const f16* __restrict__ M2h, const f16* __restrict__ M2l,
    const f16* __restrict__ W2th, const f16* __restrict__ W2tl,
    const float* __restrict__ b2, float* __restrict__ h2s)
{
  __shared__ __align__(16) f16 lds[69632];
  f32x4 acc[2] = {};
  const int t = threadIdx.x, lane = t & 63, w = t >> 6;
  const int wr = w >> 1, wc = w & 1;
  const int b = blockIdx.x;
  const int row0 = (b >> 3) * 64, col0 = (b & 7) * 64;
  mgemm_core(M2h, M2l, W2th, W2tl, DD, row0, col0, lds, acc);
#pragma unroll
  for (int q = 0; q < 4; ++q) {
    const int r = row0 + wr * 16 + (lane >> 4) * 4 + q;
#pragma unroll
    for (int n = 0; n < 2; ++n) {
      const int c = col0 + wc * 32 + n * 16 + (lane & 15);
      const float v = fmaxf(acc[n][q] + b2[c], 0.f);
      h2s[(size_t)r * DD + c] = v;
    }
  }
}

// ===== K7: preds = h2 @ fcw + fcb (A staged from fp32 h2s, split inline) ===
__global__ __launch_bounds__(GT) void fc_k(
    const float* __restrict__ h2s,
    const f16* __restrict__ fwth, const f16* __restrict__ fwtl,
    const float* __restrict__ fcb, float* __restrict__ out)
{
  __shared__ __align__(16) f16 lds[69632];
  f32x4 acc[2] = {};
  const int t = threadIdx.x, lane = t & 63, w = t >> 6;
  const int wr = w >> 1, wc = w & 1;
  const int b = blockIdx.x;
  const int row0 = (b >> 1) * 64, col0 = (b & 1) * 64;
  const bool isA = t < 256;
  const int tt = t & 255;
  const int srow = tt >> 2, su = tt & 3;
  const int lw = srow * LROW + su * 32;
  const size_t aoff = (size_t)(row0 + srow) * DD + su * 32;
  const size_t boff = (size_t)(col0 + srow) * DD + su * 32;
  const int fra = wr * 16 + (lane & 15);
  const int frb = wc * 32 + (lane & 15);
  const int fu  = (lane >> 4) * 8;
  f32x4 qa[8];
  auto loadS = [&](int k) {
    if (isA) {
#pragma unroll
      for (int i = 0; i < 8; ++i)
        qa[i] = *(const f32x4*)(h2s + aoff + k + i * 4);
    } else {
#pragma unroll
      for (int i = 0; i < 4; ++i) {
        qa[i]     = *(const f32x4*)(fwth + boff + k + i * 8);
        qa[4 + i] = *(const f32x4*)(fwtl + boff + k + i * 8);
      }
    }
  };
  auto storeS = [&](f16* wb) {
    if (isA) {
#pragma unroll
      for (int g = 0; g < 2; ++g) {
        f16x8 h0, h1v, l0, l1v;
#pragma unroll
        for (int j = 0; j < 16; ++j) {
          const float v = qa[g * 4 + (j >> 2)][j & 3];
          if (j < 8) { h0[j] = hif(v); l0[j] = lof(v); }
          else       { h1v[j - 8] = hif(v); l1v[j - 8] = lof(v); }
        }
        *(f16x8*)(wb + lw + g * 16)              = h0;
        *(f16x8*)(wb + lw + g * 16 + 8)          = h1v;
        *(f16x8*)(wb + SEC_AL + lw + g * 16)     = l0;
        *(f16x8*)(wb + SEC_AL + lw + g * 16 + 8) = l1v;
      }
    } else {
#pragma unroll
      for (int i = 0; i < 4; ++i) {
        *(f32x4*)(wb + SEC_BH + lw + i * 8) = qa[i];
        *(f32x4*)(wb + SEC_BL + lw + i * 8) = qa[4 + i];
      }
    }
  };
  loadS(0);
  storeS(lds);
  loadS(128);
  __syncthreads();
  int cur = 0;
  for (int kt = 128; kt <= DD; kt += 128) {
    f16* rb = lds + cur * BUFSZ;
    f16* wb = lds + (cur ^ 1) * BUFSZ;
    f16x8 ah[4], al[4], bh0[4], bl0[4], bh1[4], bl1[4];
#pragma unroll
    for (int s = 0; s < 4; ++s) {
      ah[s]  = *(const f16x8*)(rb + fra * LROW + s * 32 + fu);
      al[s]  = *(const f16x8*)(rb + SEC_AL + fra * LROW + s * 32 + fu);
      bh0[s] = *(const f16x8*)(rb + SEC_BH + frb * LROW + s * 32 + fu);
      bl0[s] = *(const f16x8*)(rb + SEC_BL + frb * LROW + s * 32 + fu);
      bh1[s] = *(const f16x8*)(rb + SEC_BH + (frb + 16) * LROW + s * 32 + fu);
      bl1[s] = *(const f16x8*)(rb + SEC_BL + (frb + 16) * LROW + s * 32 + fu);
    }
    if (kt < DD) {
      storeS(wb);
      if (kt + 128 < DD) loadS(kt + 128);
    }
#pragma unroll
    for (int s = 0; s < 4; ++s) {
      acc[0] = MFMA16(ah[s], bh0[s], acc[0]);
      acc[0] = MFMA16(al[s], bh0[s], acc[0]);
      acc[0] = MFMA16(ah[s], bl0[s], acc[0]);
    }
#pragma unroll
    for (int s = 0; s < 4; ++s) {
      acc[1] = MFMA16(ah[s], bh1[s], acc[1]);
      acc[1] = MFMA16(al[s], bh1[s], acc[1]);
      acc[1] = MFMA16(ah[s], bl1[s], acc[1]);
    }
    __syncthreads();
    cur ^= 1;
  }
#pragma unroll
  for (int q = 0; q < 4; ++q) {
    const int r = row0 + wr * 16 + (lane >> 4) * 4 + q;
#pragma unroll
    for (int n = 0; n < 2; ++n) {
      const int c = col0 + wc * 32 + n * 16 + (lane & 15);
      if (c < CC) out[(size_t)r * CC + c] = acc[n][q] + fcb[c];
    }
  }
}

extern "C" void kernel_launch(void* const* d_in, const int* in_sizes, int n_in,
                              void* d_out, int out_size, void* d_ws, size_t ws_size,
                              hipStream_t stream)
{
  const float* x    = (const float*)d_in[0];
  const float* prox = (const float*)d_in[1];
  const float* W1   = (const float*)d_in[2];
  const float* as1  = (const float*)d_in[3];
  const float* ad1  = (const float*)d_in[4];
  const float* b1   = (const float*)d_in[5];
  const float* W2   = (const float*)d_in[6];
  const float* as2  = (const float*)d_in[7];
  const float* ad2  = (const float*)d_in[8];
  const float* b2   = (const float*)d_in[9];
  const float* fcw  = (const float*)d_in[10];
  const float* fcb  = (const float*)d_in[11];
  float* out = (float*)d_out;

  // fp32 workspace
  float* F = (float*)d_ws;
  float* h1   = F; F += (size_t)NN * DD;
  float* ls1  = F; F += 1152;
  float* ld1  = F; F += 1152;
  float* ls2  = F; F += 1152;
  float* ld2  = F; F += 1152;
  float* v1s  = F; F += DD;
  float* v1d  = F; F += DD;
  float* v2s  = F; F += DD;
  float* v2d  = F; F += DD;
  float* M1pf = F; F += (size_t)128 * DD;  // proxy split-K partials (fp32)
  float* zP   = F; F += 128;               // proxy denominator partials
  // f16 split workspace (all bases 16B aligned; sizes multiples of 8 halves)
  f16* H = (f16*)F;
  f16* M1h  = H; H += (size_t)1152 * DD;   // rows: 100 prox(unused) + 1024 samp
  f16* M1l  = H; H += (size_t)1152 * DD;
  f16* M2h  = H; H += (size_t)NS * DD;
  f16* M2l  = H; H += (size_t)NS * DD;
  f16* xth  = H; H += (size_t)DD * NS;     // x^T  [512][1024]
  f16* xtl  = H; H += (size_t)DD * NS;
  f16* pth  = H; H += (size_t)DD * 128;    // prox^T [512][128] (k-pad zeroed)
  f16* ptl  = H; H += (size_t)DD * 128;
  f16* W1th = H; H += (size_t)DD * DD;     // W1^T [512][512]
  f16* W1tl = H; H += (size_t)DD * DD;
  f16* W2th = H; H += (size_t)DD * DD;
  f16* W2tl = H; H += (size_t)DD * DD;
  f16* fwth = H; H += (size_t)128 * DD;    // fcw^T [128][512] (k-pad zeroed)
  f16* fwtl = H; H += (size_t)128 * DD;
  f16* h1pth = H; H += (size_t)DD * 128;   // h1 proxy rows ^T [512][128]
  f16* h1ptl = H; H += (size_t)DD * 128;
  float* h2s = out + (size_t)NS * CC;      // layer-2 sample out in d_out

  // K1: weight matvecs + zero ls2/ld2 + zero M1pf/zP
  prep1_k<<<dim3(273), dim3(NTHR), 0, stream>>>(W1, W2, as1, ad1, as2, ad2,
                                                v1s, v1d, v2s, v2d, ls2, ld2,
                                                M1pf, zP);
  // K2: transposes/splits + layer-1 logits
  prep2_k<<<dim3(569), dim3(NTHR), 0, stream>>>(x, prox, W1, W2, fcw, v1s, v1d,
      xth, xtl, pth, ptl, W1th, W1tl, W2th, W2tl, fwth, fwtl, ls1, ld1);
  // K3: layer-1 aggregation (samples fused-SM + proxy split-K partials)
  agg1x_k<<<dim3(192), dim3(GT), 0, stream>>>(ls1, ld1, pth, ptl, xth, xtl,
                                              x, M1pf, zP, M1h, M1l);
  // K4: h1 (proxy finalize inline) + proxy^T splits + atomic layer-2 logits
  h1_k<<<dim3(144), dim3(GT), 0, stream>>>(M1h, M1l, M1pf, zP, ls1, ld1, prox,
                                           W1th, W1tl, b1, v2s, v2d,
                                           h1, h1pth, h1ptl, ls2, ld2);
  // K5: layer-2 aggregation (softmax fused) -> M2 splits
  agg2x_k<<<dim3(128), dim3(GT), 0, stream>>>(ls2, ld2, h1pth, h1ptl, h1,
                                              M2h, M2l);
  // K6: h2 = relu(M2@W2+b2) -> d_out (fp32 only)
  h2_k<<<dim3(128), dim3(GT), 0, stream>>>(M2h, M2l, W2th, W2tl, b2, h2s);
  // K7: preds = h2 @ fcw + fcb (A staged from fp32 h2s)
  fc_k<<<dim3(32), dim3(GT), 0, stream>>>(h2s, fwth, fwtl, fcb, out);
}

// Round 15
// 139.108 us; speedup vs baseline: 1.0578x; 1.0578x over previous
//
#include <hip/hip_runtime.h>

// Problem constants (complete bipartite proxy<->sample + self-loops)
#define PP 100    // proxies
#define NS 1024   // samples
#define NN 1124   // total nodes
#define DD 512    // feature dim
#define CC 100    // fc out dim
#define NTHR 256  // prep kernels
#define GT  512   // GEMM kernels (8 waves: 4 row x 2 col of 16x32)

typedef _Float16 f16;
typedef _Float16 f16x8 __attribute__((ext_vector_type(8)));
typedef float    f32x4 __attribute__((ext_vector_type(4)));

__device__ __forceinline__ float lk(float v) { return v > 0.f ? v : 0.2f * v; }
__device__ __forceinline__ f16 hif(float v) { return (f16)v; }
__device__ __forceinline__ f16 lof(float v) { return (f16)(v - (float)((f16)v)); }

#define MFMA16(a, b, c) __builtin_amdgcn_mfma_f32_16x16x32_f16(a, b, c, 0, 0, 0)

// LDS (BK=64): rows of 72 halves (64 + 8 pad). Sections within one buffer:
// Ash=0, Asl=4608, Bsh=9216, Bsl=13824; buffer size 18432 halves.
// Double-buffered: buf k at lds + k*18432 (36864 halves = 72 KiB total).
// 512-thread role split: t<256 stages A (row tt>>2, 16-half unit tt&3),
// t>=256 stages B. Waves: wr=w>>1 rows [wr*16..), wc=w&1 cols [wc*32..);
// per wave acc[2], 12 MFMA per K-step (two k-slices of 32).
#define LROW   72
#define SEC_AL 4608
#define SEC_BH 9216
#define SEC_BL 13824
#define BUFSZ  18432

// =================== MFMA split-f16 GEMM core (512 thr, BK=64) =============
__device__ __forceinline__ void mgemm_core(
    const f16* __restrict__ Ah, const f16* __restrict__ Al,
    const f16* __restrict__ Bth, const f16* __restrict__ Btl,
    int K, int row0, int col0, f16* __restrict__ lds, f32x4 acc[2])
{
  const int t = threadIdx.x;
  const int lane = t & 63, w = t >> 6;
  const int wr = w >> 1, wc = w & 1;
  const bool isA = t < 256;
  const int tt = t & 255;
  const int srow = tt >> 2, su = tt & 3;
  const int lw = srow * LROW + su * 16;
  const int sec0 = isA ? 0 : SEC_BH, sec1 = isA ? SEC_AL : SEC_BL;
  const f16* g0 = isA ? Ah : Bth;
  const f16* g1 = isA ? Al : Btl;
  const size_t goff = (size_t)((isA ? row0 : col0) + srow) * K + su * 16;
  const int fra = wr * 16 + (lane & 15);
  const int frb = wc * 32 + (lane & 15);
  const int fu  = (lane >> 4) * 8;
  f32x4 p0 = *(const f32x4*)(g0 + goff);
  f32x4 p1 = *(const f32x4*)(g0 + goff + 8);
  f32x4 p2 = *(const f32x4*)(g1 + goff);
  f32x4 p3 = *(const f32x4*)(g1 + goff + 8);
  *(f32x4*)(lds + sec0 + lw)     = p0;
  *(f32x4*)(lds + sec0 + lw + 8) = p1;
  *(f32x4*)(lds + sec1 + lw)     = p2;
  *(f32x4*)(lds + sec1 + lw + 8) = p3;
  if (K > 64) {
    p0 = *(const f32x4*)(g0 + goff + 64);
    p1 = *(const f32x4*)(g0 + goff + 72);
    p2 = *(const f32x4*)(g1 + goff + 64);
    p3 = *(const f32x4*)(g1 + goff + 72);
  }
  __syncthreads();
  int cur = 0;
  for (int kt = 64; kt <= K; kt += 64) {
    f16* rb = lds + cur * BUFSZ;
    f16* wb = lds + (cur ^ 1) * BUFSZ;
    f16x8 ah0  = *(const f16x8*)(rb + fra * LROW + fu);
    f16x8 ah1  = *(const f16x8*)(rb + fra * LROW + 32 + fu);
    f16x8 al0  = *(const f16x8*)(rb + SEC_AL + fra * LROW + fu);
    f16x8 al1  = *(const f16x8*)(rb + SEC_AL + fra * LROW + 32 + fu);
    f16x8 bh00 = *(const f16x8*)(rb + SEC_BH + frb * LROW + fu);
    f16x8 bh01 = *(const f16x8*)(rb + SEC_BH + frb * LROW + 32 + fu);
    f16x8 bl00 = *(const f16x8*)(rb + SEC_BL + frb * LROW + fu);
    f16x8 bl01 = *(const f16x8*)(rb + SEC_BL + frb * LROW + 32 + fu);
    f16x8 bh10 = *(const f16x8*)(rb + SEC_BH + (frb + 16) * LROW + fu);
    f16x8 bh11 = *(const f16x8*)(rb + SEC_BH + (frb + 16) * LROW + 32 + fu);
    f16x8 bl10 = *(const f16x8*)(rb + SEC_BL + (frb + 16) * LROW + fu);
    f16x8 bl11 = *(const f16x8*)(rb + SEC_BL + (frb + 16) * LROW + 32 + fu);
    if (kt < K) {
      *(f32x4*)(wb + sec0 + lw)     = p0;
      *(f32x4*)(wb + sec0 + lw + 8) = p1;
      *(f32x4*)(wb + sec1 + lw)     = p2;
      *(f32x4*)(wb + sec1 + lw + 8) = p3;
      if (kt + 64 < K) {
        p0 = *(const f32x4*)(g0 + goff + kt + 64);
        p1 = *(const f32x4*)(g0 + goff + kt + 72);
        p2 = *(const f32x4*)(g1 + goff + kt + 64);
        p3 = *(const f32x4*)(g1 + goff + kt + 72);
      }
    }
    acc[0] = MFMA16(ah0, bh00, acc[0]);
    acc[0] = MFMA16(al0, bh00, acc[0]);
    acc[0] = MFMA16(ah0, bl00, acc[0]);
    acc[0] = MFMA16(ah1, bh01, acc[0]);
    acc[0] = MFMA16(al1, bh01, acc[0]);
    acc[0] = MFMA16(ah1, bl01, acc[0]);
    acc[1] = MFMA16(ah0, bh10, acc[1]);
    acc[1] = MFMA16(al0, bh10, acc[1]);
    acc[1] = MFMA16(ah0, bl10, acc[1]);
    acc[1] = MFMA16(ah1, bh11, acc[1]);
    acc[1] = MFMA16(al1, bh11, acc[1]);
    acc[1] = MFMA16(ah1, bl11, acc[1]);
    __syncthreads();
    cur ^= 1;
  }
}

// ============ fused softmax+aggregation GEMM (short-K, 512 thr, BK=64) =====
__device__ __forceinline__ void agg_core(
    const float* __restrict__ lsrc, int kvalid,
    const float* __restrict__ ldb, const float* __restrict__ lsb,
    const f16* __restrict__ Bth, const f16* __restrict__ Btl,
    int K, int row0, int col0, int rvalid,
    const float* __restrict__ selfv,
    f16* __restrict__ outh, f16* __restrict__ outl,
    f16* __restrict__ lds, float* __restrict__ fred)
{
  const int t = threadIdx.x, lane = t & 63, w = t >> 6;
  const int wr = w >> 1, wc = w & 1;
  float* zred = fred;          // [256]
  float* res  = fred + 256;    // [64] self exps
  float* riz  = fred + 320;    // [64] 1/denominator
  float sm = -1e30f;
  for (int k = t; k < kvalid; k += GT) sm = fmaxf(sm, lsrc[k]);
#pragma unroll
  for (int off = 1; off < 64; off <<= 1) sm = fmaxf(sm, __shfl_xor(sm, off));
  if (lane == 0) zred[w] = sm;
  __syncthreads();
  sm = fmaxf(fmaxf(fmaxf(zred[0], zred[1]), fmaxf(zred[2], zred[3])),
             fmaxf(fmaxf(zred[4], zred[5]), fmaxf(zred[6], zred[7])));
  __syncthreads();
  const bool isA = t < 256;
  const int tt = t & 255;
  const int srow = tt >> 2, su = tt & 3;
  const int lw = srow * LROW + su * 16;
  bool rok = false; float ldr = 0.f, mr = 0.f;
  if (isA && (row0 + srow) < rvalid) {
    rok = true;
    ldr = ldb[row0 + srow];
    mr  = lk(fmaxf(sm, lsb[row0 + srow]) + ldr);
  }
  const size_t boff = (size_t)(col0 + srow) * K + su * 16;
  const int fra = wr * 16 + (lane & 15);
  const int frb = wc * 32 + (lane & 15);
  const int fu  = (lane >> 4) * 8;
  f32x4 acc[2] = {};
  float zacc = 0.f;
  f32x4 p0, p1, p2, p3;
  auto prefetch = [&](int k) {
    if (isA) {
      p0 = *(const f32x4*)(lsrc + k + su * 16);
      p1 = *(const f32x4*)(lsrc + k + su * 16 + 4);
      p2 = *(const f32x4*)(lsrc + k + su * 16 + 8);
      p3 = *(const f32x4*)(lsrc + k + su * 16 + 12);
    } else {
      p0 = *(const f32x4*)(Bth + boff + k);
      p1 = *(const f32x4*)(Bth + boff + k + 8);
      p2 = *(const f32x4*)(Btl + boff + k);
      p3 = *(const f32x4*)(Btl + boff + k + 8);
    }
  };
  auto stage = [&](f16* buf, int kbase) {
    if (isA) {
      f16x8 h0, l0, h1v, l1v;
#pragma unroll
      for (int j = 0; j < 16; ++j) {
        const int k = kbase + su * 16 + j;
        const float lv = (j < 4) ? p0[j] : (j < 8) ? p1[j - 4]
                       : (j < 12) ? p2[j - 8] : p3[j - 12];
        float f = 0.f;
        if (rok && k < kvalid) f = __expf(lk(lv + ldr) - mr);
        zacc += f;
        if (j < 8) { h0[j] = hif(f); l0[j] = lof(f); }
        else       { h1v[j - 8] = hif(f); l1v[j - 8] = lof(f); }
      }
      *(f16x8*)(buf + lw)              = h0;
      *(f16x8*)(buf + lw + 8)          = h1v;
      *(f16x8*)(buf + SEC_AL + lw)     = l0;
      *(f16x8*)(buf + SEC_AL + lw + 8) = l1v;
    } else {
      *(f32x4*)(buf + SEC_BH + lw)     = p0;
      *(f32x4*)(buf + SEC_BH + lw + 8) = p1;
      *(f32x4*)(buf + SEC_BL + lw)     = p2;
      *(f32x4*)(buf + SEC_BL + lw + 8) = p3;
    }
  };
  prefetch(0);
  stage(lds, 0);
  if (K > 64) prefetch(64);
  __syncthreads();
  int cur = 0;
  for (int kt = 64; kt <= K; kt += 64) {
    f16* rb = lds + cur * BUFSZ;
    f16* wb = lds + (cur ^ 1) * BUFSZ;
    f16x8 ah0  = *(const f16x8*)(rb + fra * LROW + fu);
    f16x8 ah1  = *(const f16x8*)(rb + fra * LROW + 32 + fu);
    f16x8 al0  = *(const f16x8*)(rb + SEC_AL + fra * LROW + fu);
    f16x8 al1  = *(const f16x8*)(rb + SEC_AL + fra * LROW + 32 + fu);
    f16x8 bh00 = *(const f16x8*)(rb + SEC_BH + frb * LROW + fu);
    f16x8 bh01 = *(const f16x8*)(rb + SEC_BH + frb * LROW + 32 + fu);
    f16x8 bl00 = *(const f16x8*)(rb + SEC_BL + frb * LROW + fu);
    f16x8 bl01 = *(const f16x8*)(rb + SEC_BL + frb * LROW + 32 + fu);
    f16x8 bh10 = *(const f16x8*)(rb + SEC_BH + (frb + 16) * LROW + fu);
    f16x8 bh11 = *(const f16x8*)(rb + SEC_BH + (frb + 16) * LROW + 32 + fu);
    f16x8 bl10 = *(const f16x8*)(rb + SEC_BL + (frb + 16) * LROW + fu);
    f16x8 bl11 = *(const f16x8*)(rb + SEC_BL + (frb + 16) * LROW + 32 + fu);
    if (kt < K) {
      stage(wb, kt);
      if (kt + 64 < K) prefetch(kt + 64);
    }
    acc[0] = MFMA16(ah0, bh00, acc[0]);
    acc[0] = MFMA16(al0, bh00, acc[0]);
    acc[0] = MFMA16(ah0, bl00, acc[0]);
    acc[0] = MFMA16(ah1, bh01, acc[0]);
    acc[0] = MFMA16(al1, bh01, acc[0]);
    acc[0] = MFMA16(ah1, bl01, acc[0]);
    acc[1] = MFMA16(ah0, bh10, acc[1]);
    acc[1] = MFMA16(al0, bh10, acc[1]);
    acc[1] = MFMA16(ah0, bl10, acc[1]);
    acc[1] = MFMA16(ah1, bh11, acc[1]);
    acc[1] = MFMA16(al1, bh11, acc[1]);
    acc[1] = MFMA16(ah1, bl11, acc[1]);
    __syncthreads();
    cur ^= 1;
  }
  if (t < 256) zred[t] = zacc;
  __syncthreads();
  if (t < 64) {
    float z = zred[t * 4] + zred[t * 4 + 1] + zred[t * 4 + 2] + zred[t * 4 + 3];
    float es = 0.f, iz = 0.f;
    if (row0 + t < rvalid) {
      const float l2 = ldb[row0 + t], s2 = lsb[row0 + t];
      const float m2 = lk(fmaxf(sm, s2) + l2);
      es = __expf(lk(s2 + l2) - m2);
      iz = 1.f / (z + es);
    }
    res[t] = es; riz[t] = iz;
  }
  __syncthreads();
#pragma unroll
  for (int q = 0; q < 4; ++q) {
    const int rl = wr * 16 + (lane >> 4) * 4 + q;
    const int gr = row0 + rl;
    if (gr >= rvalid) continue;
    const float es = res[rl], iz = riz[rl];
#pragma unroll
    for (int n = 0; n < 2; ++n) {
      const int c = col0 + wc * 32 + n * 16 + (lane & 15);
      const float v = (acc[n][q] + es * selfv[(size_t)gr * DD + c]) * iz;
      outh[(size_t)gr * DD + c] = hif(v);
      outl[(size_t)gr * DD + c] = lof(v);
    }
  }
}

// ======== 64x64 direct transpose+split tile (no LDS, one pass) =============
__device__ __forceinline__ void cvt_tile(
    const float* __restrict__ in, int R, int Cin,
    f16* __restrict__ oh, f16* __restrict__ ol, int ldo,
    int ti, int tj)
{
  const int t = threadIdx.x;
  const int gj0 = tj * 64 + (t & 31) * 2;
  const int i8  = (t >> 5) * 8;
  const bool c0 = gj0 < Cin, c1 = (gj0 + 1) < Cin;
  f16x8 vh0, vl0, vh1, vl1;
#pragma unroll
  for (int e = 0; e < 8; ++e) {
    const int gi = ti * 64 + i8 + e;
    float a = 0.f, b = 0.f;
    if (gi < R) {
      if (c0 && c1) {
        const float2 v = *(const float2*)(in + (size_t)gi * Cin + gj0);
        a = v.x; b = v.y;
      } else if (c0) {
        a = in[(size_t)gi * Cin + gj0];
      }
    }
    vh0[e] = hif(a); vl0[e] = lof(a);
    vh1[e] = hif(b); vl1[e] = lof(b);
  }
  const size_t o0 = (size_t)gj0 * ldo + ti * 64 + i8;
  *(f16x8*)(oh + o0) = vh0;
  *(f16x8*)(ol + o0) = vl0;
  const size_t o1 = o0 + ldo;
  *(f16x8*)(oh + o1) = vh1;
  *(f16x8*)(ol + o1) = vl1;
}

// ===== K1: weight matvecs + zero ls2/ld2 + zero M1pf/zP ====================
__global__ __launch_bounds__(NTHR) void prep1_k(
    const float* __restrict__ W1, const float* __restrict__ W2,
    const float* __restrict__ as1, const float* __restrict__ ad1,
    const float* __restrict__ as2, const float* __restrict__ ad2,
    float* __restrict__ v1s, float* __restrict__ v1d,
    float* __restrict__ v2s, float* __restrict__ v2d,
    float* __restrict__ ls2, float* __restrict__ ld2,
    float* __restrict__ M1pf, float* __restrict__ zP)
{
  const int u = blockIdx.x;
  if (u < 256) {
    const int wid  = u * 4 + (threadIdx.x >> 6);
    const int lane = threadIdx.x & 63;
    const int r = wid & 511;
    const bool l1 = (wid < 512);
    const float* W = l1 ? W1 : W2;
    const float4* a4 = (const float4*)(l1 ? as1 : as2);
    const float4* b4 = (const float4*)(l1 ? ad1 : ad2);
    const float4* w4 = (const float4*)(W + (size_t)r * DD);
    float4 w0 = w4[lane], w1 = w4[lane + 64];
    float4 a0 = a4[lane], a1 = a4[lane + 64];
    float4 b0 = b4[lane], b1 = b4[lane + 64];
    float s1 = w0.x * a0.x + w0.y * a0.y + w0.z * a0.z + w0.w * a0.w
             + w1.x * a1.x + w1.y * a1.y + w1.z * a1.z + w1.w * a1.w;
    float s2 = w0.x * b0.x + w0.y * b0.y + w0.z * b0.z + w0.w * b0.w
             + w1.x * b1.x + w1.y * b1.y + w1.z * b1.z + w1.w * b1.w;
#pragma unroll
    for (int off = 32; off > 0; off >>= 1) {
      s1 += __shfl_down(s1, off);
      s2 += __shfl_down(s2, off);
    }
    if (lane == 0) {
      (l1 ? v1s : v2s)[r] = s1;
      (l1 ? v1d : v2d)[r] = s2;
    }
  } else if (u == 256) {
    for (int i = threadIdx.x; i < 1152; i += NTHR) { ls2[i] = 0.f; ld2[i] = 0.f; }
    if (threadIdx.x < 128) zP[threadIdx.x] = 0.f;
  } else {
    float4* p4 = (float4*)M1pf + (size_t)(u - 257) * 800;
#pragma unroll
    for (int p = 0; p < 4; ++p) {
      const int i = threadIdx.x + p * 256;
      if (i < 800) p4[i] = make_float4(0.f, 0.f, 0.f, 0.f);
    }
  }
}

// ===== K2: transposes/splits + layer-1 logits ==============================
__global__ __launch_bounds__(NTHR) void prep2_k(
    const float* __restrict__ x, const float* __restrict__ prox,
    const float* __restrict__ W1, const float* __restrict__ W2,
    const float* __restrict__ fcw,
    const float* __restrict__ v1s, const float* __restrict__ v1d,
    f16* xth, f16* xtl, f16* pth, f16* ptl,
    f16* W1th, f16* W1tl, f16* W2th, f16* W2tl, f16* fwth, f16* fwtl,
    float* __restrict__ ls1, float* __restrict__ ld1)
{
  const int b = blockIdx.x;
  if (b < 64) {
    cvt_tile(W1, 512, 512, W1th, W1tl, 512, b >> 3, b & 7);
  } else if (b < 128) {
    cvt_tile(W2, 512, 512, W2th, W2tl, 512, (b - 64) >> 3, (b - 64) & 7);
  } else if (b < 256) {
    cvt_tile(x, NS, 512, xth, xtl, NS, (b - 128) >> 3, (b - 128) & 7);
  } else if (b < 272) {
    cvt_tile(prox, PP, 512, pth, ptl, 128, (b - 256) >> 3, (b - 256) & 7);
  } else if (b < 288) {
    cvt_tile(fcw, 512, CC, fwth, fwtl, 512, (b - 272) >> 1, (b - 272) & 1);
  } else {
    const int r    = (b - 288) * 4 + (threadIdx.x >> 6);
    const int lane = threadIdx.x & 63;
    if (r >= NN) return;
    const float* row = (r < PP) ? prox + (size_t)r * DD
                                : x + (size_t)(r - PP) * DD;
    const float4* r4 = (const float4*)row;
    const float4* s4 = (const float4*)v1s;
    const float4* d4 = (const float4*)v1d;
    float4 v0 = r4[lane], v1 = r4[lane + 64];
    float4 a0 = s4[lane], a1 = s4[lane + 64];
    float4 b0 = d4[lane], b1 = d4[lane + 64];
    float s1 = v0.x * a0.x + v0.y * a0.y + v0.z * a0.z + v0.w * a0.w
             + v1.x * a1.x + v1.y * a1.y + v1.z * a1.z + v1.w * a1.w;
    float s2 = v0.x * b0.x + v0.y * b0.y + v0.z * b0.z + v0.w * b0.w
             + v1.x * b1.x + v1.y * b1.y + v1.z * b1.z + v1.w * b1.w;
#pragma unroll
    for (int off = 32; off > 0; off >>= 1) {
      s1 += __shfl_down(s1, off);
      s2 += __shfl_down(s2, off);
    }
    if (lane == 0) { ls1[r] = s1; ld1[r] = s2; }
  }
}

// ===== K3: layer-1 aggregation (512 thr, BK=64) ============================
// blocks [0,128): sample dsts (fused softmax, K=128)
// blocks [128,192): proxy split-K partials (16 tiles x 4 chunks of 256)
__global__ __launch_bounds__(GT) void agg1x_k(
    const float* __restrict__ ls1, const float* __restrict__ ld1,
    const f16* __restrict__ pth, const f16* __restrict__ ptl,
    const f16* __restrict__ xth, const f16* __restrict__ xtl,
    const float* __restrict__ x,
    float* __restrict__ M1pf, float* __restrict__ zP,
    f16* __restrict__ M1h, f16* __restrict__ M1l)
{
  __shared__ __align__(16) f16 lds[36864];
  __shared__ float fred[384];
  const int b = blockIdx.x;
  if (b < 128) {
    const int row0 = (b >> 3) * 64, col0 = (b & 7) * 64;
    agg_core(ls1, PP, ld1 + PP, ls1 + PP, pth, ptl, 128, row0, col0, NS,
             x, M1h + (size_t)PP * DD, M1l + (size_t)PP * DD, lds, fred);
    return;
  }
  // ---- proxy split-K partial ----
  const int t = threadIdx.x, lane = t & 63, w = t >> 6;
  const int wr = w >> 1, wc = w & 1;
  const int b2 = b - 128;
  const int tile = b2 >> 2, chunk = b2 & 3;
  const int row0 = (tile >> 3) * 64, col0 = (tile & 7) * 64;
  const int k0 = chunk * 256;
  const float* lsrc = ls1 + PP;
  float sm = -1e30f;
  for (int k = t; k < NS; k += GT) sm = fmaxf(sm, lsrc[k]);
#pragma unroll
  for (int off = 1; off < 64; off <<= 1) sm = fmaxf(sm, __shfl_xor(sm, off));
  if (lane == 0) fred[w] = sm;
  __syncthreads();
  sm = fmaxf(fmaxf(fmaxf(fred[0], fred[1]), fmaxf(fred[2], fred[3])),
             fmaxf(fmaxf(fred[4], fred[5]), fmaxf(fred[6], fred[7])));
  __syncthreads();
  const bool isA = t < 256;
  const int tt = t & 255;
  const int srow = tt >> 2, su = tt & 3;
  const int lw = srow * LROW + su * 16;
  bool rok = false; float ldr = 0.f, mr = 0.f;
  if (isA && (row0 + srow) < PP) {
    rok = true;
    ldr = ld1[row0 + srow];
    mr  = lk(fmaxf(sm, ls1[row0 + srow]) + ldr);
  }
  const size_t boff = (size_t)(col0 + srow) * NS + k0 + su * 16;
  const int fra = wr * 16 + (lane & 15);
  const int frb = wc * 32 + (lane & 15);
  const int fu  = (lane >> 4) * 8;
  f32x4 acc[2] = {};
  float zacc = 0.f;
  f32x4 p0, p1, p2, p3;
  auto prefetch = [&](int k) {
    if (isA) {
      p0 = *(const f32x4*)(lsrc + k0 + k + su * 16);
      p1 = *(const f32x4*)(lsrc + k0 + k + su * 16 + 4);
      p2 = *(const f32x4*)(lsrc + k0 + k + su * 16 + 8);
      p3 = *(const f32x4*)(lsrc + k0 + k + su * 16 + 12);
    } else {
      p0 = *(const f32x4*)(xth + boff + k);
      p1 = *(const f32x4*)(xth + boff + k + 8);
      p2 = *(const f32x4*)(xtl + boff + k);
      p3 = *(const f32x4*)(xtl + boff + k + 8);
    }
  };
  auto stage = [&](f16* buf) {
    if (isA) {
      f16x8 h0, l0, h1v, l1v;
#pragma unroll
      for (int j = 0; j < 16; ++j) {
        const float lv = (j < 4) ? p0[j] : (j < 8) ? p1[j - 4]
                       : (j < 12) ? p2[j - 8] : p3[j - 12];
        float f = 0.f;
        if (rok) f = __expf(lk(lv + ldr) - mr);
        zacc += f;
        if (j < 8) { h0[j] = hif(f); l0[j] = lof(f); }
        else       { h1v[j - 8] = hif(f); l1v[j - 8] = lof(f); }
      }
      *(f16x8*)(buf + lw)              = h0;
      *(f16x8*)(buf + lw + 8)          = h1v;
      *(f16x8*)(buf + SEC_AL + lw)     = l0;
      *(f16x8*)(buf + SEC_AL + lw + 8) = l1v;
    } else {
      *(f32x4*)(buf + SEC_BH + lw)     = p0;
      *(f32x4*)(buf + SEC_BH + lw + 8) = p1;
      *(f32x4*)(buf + SEC_BL + lw)     = p2;
      *(f32x4*)(buf + SEC_BL + lw + 8) = p3;
    }
  };
  prefetch(0);
  stage(lds);
  prefetch(64);
  __syncthreads();
  int cur = 0;
  for (int kt = 64; kt <= 256; kt += 64) {
    f16* rb = lds + cur * BUFSZ;
    f16* wb = lds + (cur ^ 1) * BUFSZ;
    f16x8 ah0  = *(const f16x8*)(rb + fra * LROW + fu);
    f16x8 ah1  = *(const f16x8*)(rb + fra * LROW + 32 + fu);
    f16x8 al0  = *(const f16x8*)(rb + SEC_AL + fra * LROW + fu);
    f16x8 al1  = *(const f16x8*)(rb + SEC_AL + fra * LROW + 32 + fu);
    f16x8 bh00 = *(const f16x8*)(rb + SEC_BH + frb * LROW + fu);
    f16x8 bh01 = *(const f16x8*)(rb + SEC_BH + frb * LROW + 32 + fu);
    f16x8 bl00 = *(const f16x8*)(rb + SEC_BL + frb * LROW + fu);
    f16x8 bl01 = *(const f16x8*)(rb + SEC_BL + frb * LROW + 32 + fu);
    f16x8 bh10 = *(const f16x8*)(rb + SEC_BH + (frb + 16) * LROW + fu);
    f16x8 bh11 = *(const f16x8*)(rb + SEC_BH + (frb + 16) * LROW + 32 + fu);
    f16x8 bl10 = *(const f16x8*)(rb + SEC_BL + (frb + 16) * LROW + fu);
    f16x8 bl11 = *(const f16x8*)(rb + SEC_BL + (frb + 16) * LROW + 32 + fu);
    if (kt < 256) {
      stage(wb);
      if (kt + 64 < 256) prefetch(kt + 64);
    }
    acc[0] = MFMA16(ah0, bh00, acc[0]);
    acc[0] = MFMA16(al0, bh00, acc[0]);
    acc[0] = MFMA16(ah0, bl00, acc[0]);
    acc[0] = MFMA16(ah1, bh01, acc[0]);
    acc[0] = MFMA16(al1, bh01, acc[0]);
    acc[0] = MFMA16(ah1, bl01, acc[0]);
    acc[1] = MFMA16(ah0, bh10, acc[1]);
    acc[1] = MFMA16(al0, bh10, acc[1]);
    acc[1] = MFMA16(ah0, bl10, acc[1]);
    acc[1] = MFMA16(ah1, bh11, acc[1]);
    acc[1] = MFMA16(al1, bh11, acc[1]);
    acc[1] = MFMA16(ah1, bl11, acc[1]);
    __syncthreads();
    cur ^= 1;
  }
  // z depends only on (row, chunk) — add exactly once per chunk: col0==0 only
  if (col0 == 0) {
    if (t < 256) fred[t] = zacc;
    __syncthreads();
    if (t < 64) {
      const int r = row0 + t;
      if (r < PP) {
        float z = fred[t * 4] + fred[t * 4 + 1] + fred[t * 4 + 2] + fred[t * 4 + 3];
        atomicAdd(&zP[r], z);
      }
    }
  }
#pragma unroll
  for (int q = 0; q < 4; ++q) {
    const int gr = row0 + wr * 16 + (lane >> 4) * 4 + q;
    if (gr >= PP) continue;
#pragma unroll
    for (int n = 0; n < 2; ++n) {
      const int c = col0 + wc * 32 + n * 16 + (lane & 15);
      atomicAdd(&M1pf[(size_t)gr * DD + c], acc[n][q]);
    }
  }
}

// ===== K4: h1 = relu(M1@W1 + b1) (512 thr, BK=64); proxy finalize inline;
//           emit proxy^T splits; atomic layer-2 logits =====================
__global__ __launch_bounds__(GT) void h1_k(
    const f16* __restrict__ M1h, const f16* __restrict__ M1l,
    const float* __restrict__ M1pf, const float* __restrict__ zP,
    const float* __restrict__ ls1, const float* __restrict__ ld1,
    const float* __restrict__ prox,
    const f16* __restrict__ W1th, const f16* __restrict__ W1tl,
    const float* __restrict__ b1,
    const float* __restrict__ v2s, const float* __restrict__ v2d,
    float* __restrict__ h1, f16* __restrict__ h1pth, f16* __restrict__ h1ptl,
    float* __restrict__ ls2, float* __restrict__ ld2)
{
  __shared__ __align__(16) f16 lds[36864];
  __shared__ float fred[384];
  float* esA = fred + 256;   // [64]
  float* izA = fred + 320;   // [64]
  const int t = threadIdx.x, lane = t & 63, w = t >> 6;
  const int wr = w >> 1, wc = w & 1;
  const int b = blockIdx.x;
  const int row0 = (b >> 3) * 64, col0 = (b & 7) * 64;
  const bool hasP = (row0 < 128);
  if (hasP) {
    float sm = -1e30f;
    for (int k = t; k < NS; k += GT) sm = fmaxf(sm, ls1[PP + k]);
#pragma unroll
    for (int off = 1; off < 64; off <<= 1) sm = fmaxf(sm, __shfl_xor(sm, off));
    if (lane == 0) fred[w] = sm;
    __syncthreads();
    sm = fmaxf(fmaxf(fmaxf(fred[0], fred[1]), fmaxf(fred[2], fred[3])),
               fmaxf(fmaxf(fred[4], fred[5]), fmaxf(fred[6], fred[7])));
    if (t < 64) {
      const int r = row0 + t;
      float es = 0.f, iz = 0.f;
      if (r < PP) {
        const float ldr = ld1[r];
        const float m = lk(fmaxf(sm, ls1[r]) + ldr);
        es = __expf(lk(ls1[r] + ldr) - m);
        iz = 1.f / (zP[r] + es);
      }
      esA[t] = es; izA[t] = iz;
    }
    __syncthreads();
  }
  // ---- GEMM with role-split staging (A: mixed-source, B: W1 splits) ----
  const bool isA = t < 256;
  const int tt = t & 255;
  const int srow = tt >> 2, su = tt & 3;
  const int lw = srow * LROW + su * 16;
  const int ar = row0 + srow;
  const bool isP = isA && (ar < PP);
  const size_t aoff = (size_t)ar * DD + su * 16;
  const size_t boff = (size_t)(col0 + srow) * DD + su * 16;
  const int fra = wr * 16 + (lane & 15);
  const int frb = wc * 32 + (lane & 15);
  const int fu  = (lane >> 4) * 8;
  const float esr = isP ? esA[srow] : 0.f;
  const float izr = isP ? izA[srow] : 0.f;
  f32x4 qa0, qa1, qa2, qa3, qb0, qb1, qb2, qb3;
  auto loadS = [&](int k) {
    if (isA) {
      if (isP) {
        qa0 = *(const f32x4*)(M1pf + aoff + k);
        qa1 = *(const f32x4*)(M1pf + aoff + k + 4);
        qa2 = *(const f32x4*)(M1pf + aoff + k + 8);
        qa3 = *(const f32x4*)(M1pf + aoff + k + 12);
        qb0 = *(const f32x4*)(prox + aoff + k);
        qb1 = *(const f32x4*)(prox + aoff + k + 4);
        qb2 = *(const f32x4*)(prox + aoff + k + 8);
        qb3 = *(const f32x4*)(prox + aoff + k + 12);
      } else {
        qa0 = *(const f32x4*)(M1h + aoff + k);
        qa1 = *(const f32x4*)(M1h + aoff + k + 8);
        qa2 = *(const f32x4*)(M1l + aoff + k);
        qa3 = *(const f32x4*)(M1l + aoff + k + 8);
      }
    } else {
      qa0 = *(const f32x4*)(W1th + boff + k);
      qa1 = *(const f32x4*)(W1th + boff + k + 8);
      qa2 = *(const f32x4*)(W1tl + boff + k);
      qa3 = *(const f32x4*)(W1tl + boff + k + 8);
    }
  };
  auto storeS = [&](f16* wb) {
    if (isA) {
      if (isP) {
        f16x8 h0, l0, h1v, l1v;
#pragma unroll
        for (int j = 0; j < 16; ++j) {
          const float pv = (j < 4) ? qa0[j] : (j < 8) ? qa1[j - 4]
                         : (j < 12) ? qa2[j - 8] : qa3[j - 12];
          const float xv = (j < 4) ? qb0[j] : (j < 8) ? qb1[j - 4]
                         : (j < 12) ? qb2[j - 8] : qb3[j - 12];
          const float v = (pv + esr * xv) * izr;
          if (j < 8) { h0[j] = hif(v); l0[j] = lof(v); }
          else       { h1v[j - 8] = hif(v); l1v[j - 8] = lof(v); }
        }
        *(f16x8*)(wb + lw)              = h0;
        *(f16x8*)(wb + lw + 8)          = h1v;
        *(f16x8*)(wb + SEC_AL + lw)     = l0;
        *(f16x8*)(wb + SEC_AL + lw + 8) = l1v;
      } else {
        *(f32x4*)(wb + lw)              = qa0;
        *(f32x4*)(wb + lw + 8)          = qa1;
        *(f32x4*)(wb + SEC_AL + lw)     = qa2;
        *(f32x4*)(wb + SEC_AL + lw + 8) = qa3;
      }
    } else {
      *(f32x4*)(wb + SEC_BH + lw)     = qa0;
      *(f32x4*)(wb + SEC_BH + lw + 8) = qa1;
      *(f32x4*)(wb + SEC_BL + lw)     = qa2;
      *(f32x4*)(wb + SEC_BL + lw + 8) = qa3;
    }
  };
  f32x4 acc[2] = {};
  loadS(0);
  storeS(lds);
  loadS(64);
  __syncthreads();
  int cur = 0;
  for (int kt = 64; kt <= DD; kt += 64) {
    f16* rb = lds + cur * BUFSZ;
    f16* wb = lds + (cur ^ 1) * BUFSZ;
    f16x8 ah0  = *(const f16x8*)(rb + fra * LROW + fu);
    f16x8 ah1  = *(const f16x8*)(rb + fra * LROW + 32 + fu);
    f16x8 al0  = *(const f16x8*)(rb + SEC_AL + fra * LROW + fu);
    f16x8 al1  = *(const f16x8*)(rb + SEC_AL + fra * LROW + 32 + fu);
    f16x8 bh00 = *(const f16x8*)(rb + SEC_BH + frb * LROW + fu);
    f16x8 bh01 = *(const f16x8*)(rb + SEC_BH + frb * LROW + 32 + fu);
    f16x8 bl00 = *(const f16x8*)(rb + SEC_BL + frb * LROW + fu);
    f16x8 bl01 = *(const f16x8*)(rb + SEC_BL + frb * LROW + 32 + fu);
    f16x8 bh10 = *(const f16x8*)(rb + SEC_BH + (frb + 16) * LROW + fu);
    f16x8 bh11 = *(const f16x8*)(rb + SEC_BH + (frb + 16) * LROW + 32 + fu);
    f16x8 bl10 = *(const f16x8*)(rb + SEC_BL + (frb + 16) * LROW + fu);
    f16x8 bl11 = *(const f16x8*)(rb + SEC_BL + (frb + 16) * LROW + 32 + fu);
    if (kt < DD) {
      storeS(wb);
      if (kt + 64 < DD) loadS(kt + 64);
    }
    acc[0] = MFMA16(ah0, bh00, acc[0]);
    acc[0] = MFMA16(al0, bh00, acc[0]);
    acc[0] = MFMA16(ah0, bl00, acc[0]);
    acc[0] = MFMA16(ah1, bh01, acc[0]);
    acc[0] = MFMA16(al1, bh01, acc[0]);
    acc[0] = MFMA16(ah1, bl01, acc[0]);
    acc[1] = MFMA16(ah0, bh10, acc[1]);
    acc[1] = MFMA16(al0, bh10, acc[1]);
    acc[1] = MFMA16(ah0, bl10, acc[1]);
    acc[1] = MFMA16(ah1, bh11, acc[1]);
    acc[1] = MFMA16(al1, bh11, acc[1]);
    acc[1] = MFMA16(ah1, bl11, acc[1]);
    __syncthreads();
    cur ^= 1;
  }
  // ---- epilogue ----
  const int c0 = col0 + wc * 32 + (lane & 15);
  const int c1 = c0 + 16;
  const float vs0 = v2s[c0], vs1 = v2s[c1];
  const float vd0 = v2d[c0], vd1 = v2d[c1];
  const float bb0 = b1[c0],  bb1 = b1[c1];
#pragma unroll
  for (int q = 0; q < 4; ++q) {
    const int r = row0 + wr * 16 + (lane >> 4) * 4 + q;
    if (r >= NN) continue;
    float ps = 0.f, pd = 0.f;
#pragma unroll
    for (int n = 0; n < 2; ++n) {
      const int c = (n == 0) ? c0 : c1;
      const float v = fmaxf(acc[n][q] + (n == 0 ? bb0 : bb1), 0.f);
      h1[(size_t)r * DD + c] = v;
      ps += v * (n == 0 ? vs0 : vs1);
      pd += v * (n == 0 ? vd0 : vd1);
      if (r < 128) {
        const size_t o = (size_t)c * 128 + r;
        f16 hh = (f16)0.f, ll = (f16)0.f;
        if (r < PP) { hh = hif(v); ll = lof(v); }
        h1pth[o] = hh; h1ptl[o] = ll;
      }
    }
#pragma unroll
    for (int off = 1; off < 16; off <<= 1) {
      ps += __shfl_xor(ps, off);
      pd += __shfl_xor(pd, off);
    }
    if ((lane & 15) == 0) {
      atomicAdd(&ls2[r], ps);
      atomicAdd(&ld2[r], pd);
    }
  }
}

// ===== K5: layer-2 aggregation (softmax fused; sample dsts only) ===========
__global__ __launch_bounds__(GT) void agg2x_k(
    const float* __restrict__ ls2, const float* __restrict__ ld2,
    const f16* __restrict__ h1pth, const f16* __restrict__ h1ptl,
    const float* __restrict__ h1,
    f16* __restrict__ M2h, f16* __restrict__ M2l)
{
  __shared__ __align__(16) f16 lds[36864];
  __shared__ float fred[384];
  const int b = blockIdx.x;
  const int row0 = (b >> 3) * 64, col0 = (b & 7) * 64;
  agg_core(ls2, PP, ld2 + PP, ls2 + PP, h1pth, h1ptl, 128, row0, col0, NS,
           h1 + (size_t)PP * DD, M2h, M2l, lds, fred);
}

// ===== K6: h2 = relu(M2@W2 + b2) -> d_out (fp32) + split for fc ============
__global__ __launch_bounds__(GT) void h2_k(
    const f16* __restrict__ M2h, const f16* __restrict__ M2l,
    const f16* __restrict__ W2th, const f16* __restrict__ W2tl,
    const float* __restrict__ b2, float* __restrict__ h2s,
    f16* __restrict__ h2h, f16* __restrict__ h2l)
{
  __shared__ __align__(16) f16 lds[36864];
  f32x4 acc[2] = {};
  const int t = threadIdx.x, lane = t & 63, w = t >> 6;
  const int wr = w >> 1, wc = w & 1;
  const int b = blockIdx.x;
  const int row0 = (b >> 3) * 64, col0 = (b & 7) * 64;
  mgemm_core(M2h, M2l, W2th, W2tl, DD, row0, col0, lds, acc);
#pragma unroll
  for (int q = 0; q < 4; ++q) {
    const int r = row0 + wr * 16 + (lane >> 4) * 4 + q;
#pragma unroll
    for (int n = 0; n < 2; ++n) {
      const int c = col0 + wc * 32 + n * 16 + (lane & 15);
      const float v = fmaxf(acc[n][q] + b2[c], 0.f);
      const size_t o = (size_t)r * DD + c;
      h2s[o] = v;
      h2h[o] = hif(v); h2l[o] = lof(v);
    }
  }
}

// ===== K7: preds = h2 @ fcw + fcb ==========================================
__global__ __launch_bounds__(GT) void fc_k(
    const f16* __restrict__ h2h, const f16* __restrict__ h2l,
    const f16* __restrict__ fwth, const f16* __restrict__ fwtl,
    const float* __restrict__ fcb, float* __restrict__ out)
{
  __shared__ __align__(16) f16 lds[36864];
  f32x4 acc[2] = {};
  const int t = threadIdx.x, lane = t & 63, w = t >> 6;
  const int wr = w >> 1, wc = w & 1;
  const int b = blockIdx.x;
  const int row0 = (b >> 1) * 64, col0 = (b & 1) * 64;
  mgemm_core(h2h, h2l, fwth, fwtl, DD, row0, col0, lds, acc);
#pragma unroll
  for (int q = 0; q < 4; ++q) {
    const int r = row0 + wr * 16 + (lane >> 4) * 4 + q;
#pragma unroll
    for (int n = 0; n < 2; ++n) {
      const int c = col0 + wc * 32 + n * 16 + (lane & 15);
      if (c < CC) out[(size_t)r * CC + c] = acc[n][q] + fcb[c];
    }
  }
}

extern "C" void kernel_launch(void* const* d_in, const int* in_sizes, int n_in,
                              void* d_out, int out_size, void* d_ws, size_t ws_size,
                              hipStream_t stream)
{
  const float* x    = (const float*)d_in[0];
  const float* prox = (const float*)d_in[1];
  const float* W1   = (const float*)d_in[2];
  const float* as1  = (const float*)d_in[3];
  const float* ad1  = (const float*)d_in[4];
  const float* b1   = (const float*)d_in[5];
  const float* W2   = (const float*)d_in[6];
  const float* as2  = (const float*)d_in[7];
  const float* ad2  = (const float*)d_in[8];
  const float* b2   = (const float*)d_in[9];
  const float* fcw  = (const float*)d_in[10];
  const float* fcb  = (const float*)d_in[11];
  float* out = (float*)d_out;

  // fp32 workspace
  float* F = (float*)d_ws;
  float* h1   = F; F += (size_t)NN * DD;
  float* ls1  = F; F += 1152;
  float* ld1  = F; F += 1152;
  float* ls2  = F; F += 1152;
  float* ld2  = F; F += 1152;
  float* v1s  = F; F += DD;
  float* v1d  = F; F += DD;
  float* v2s  = F; F += DD;
  float* v2d  = F; F += DD;
  float* M1pf = F; F += (size_t)128 * DD;  // proxy split-K partials (fp32)
  float* zP   = F; F += 128;               // proxy denominator partials
  // f16 split workspace (all bases 16B aligned; sizes multiples of 8 halves)
  f16* H = (f16*)F;
  f16* M1h  = H; H += (size_t)1152 * DD;   // rows: 100 prox(unused) + 1024 samp
  f16* M1l  = H; H += (size_t)1152 * DD;
  f16* M2h  = H; H += (size_t)NS * DD;
  f16* M2l  = H; H += (size_t)NS * DD;
  f16* xth  = H; H += (size_t)DD * NS;     // x^T  [512][1024]
  f16* xtl  = H; H += (size_t)DD * NS;
  f16* pth  = H; H += (size_t)DD * 128;    // prox^T [512][128] (k-pad zeroed)
  f16* ptl  = H; H += (size_t)DD * 128;
  f16* W1th = H; H += (size_t)DD * DD;     // W1^T [512][512]
  f16* W1tl = H; H += (size_t)DD * DD;
  f16* W2th = H; H += (size_t)DD * DD;
  f16* W2tl = H; H += (size_t)DD * DD;
  f16* fwth = H; H += (size_t)128 * DD;    // fcw^T [128][512] (k-pad zeroed)
  f16* fwtl = H; H += (size_t)128 * DD;
  f16* h2h  = H; H += (size_t)NS * DD;
  f16* h2l  = H; H += (size_t)NS * DD;
  f16* h1pth = H; H += (size_t)DD * 128;   // h1 proxy rows ^T [512][128]
  f16* h1ptl = H; H += (size_t)DD * 128;
  float* h2s = out + (size_t)NS * CC;      // layer-2 sample out in d_out

  // K1: weight matvecs + zero ls2/ld2 + zero M1pf/zP
  prep1_k<<<dim3(273), dim3(NTHR), 0, stream>>>(W1, W2, as1, ad1, as2, ad2,
                                                v1s, v1d, v2s, v2d, ls2, ld2,
                                                M1pf, zP);
  // K2: transposes/splits + layer-1 logits
  prep2_k<<<dim3(569), dim3(NTHR), 0, stream>>>(x, prox, W1, W2, fcw, v1s, v1d,
      xth, xtl, pth, ptl, W1th, W1tl, W2th, W2tl, fwth, fwtl, ls1, ld1);
  // K3: layer-1 aggregation (samples fused-SM + proxy split-K partials)
  agg1x_k<<<dim3(192), dim3(GT), 0, stream>>>(ls1, ld1, pth, ptl, xth, xtl,
                                              x, M1pf, zP, M1h, M1l);
  // K4: h1 (proxy finalize inline) + proxy^T splits + atomic layer-2 logits
  h1_k<<<dim3(144), dim3(GT), 0, stream>>>(M1h, M1l, M1pf, zP, ls1, ld1, prox,
                                           W1th, W1tl, b1, v2s, v2d,
                                           h1, h1pth, h1ptl, ls2, ld2);
  // K5: layer-2 aggregation (softmax fused) -> M2 splits
  agg2x_k<<<dim3(128), dim3(GT), 0, stream>>>(ls2, ld2, h1pth, h1ptl, h1,
                                              M2h, M2l);
  // K6: h2 = relu(M2@W2+b2) -> d_out (+ split)
  h2_k<<<dim3(128), dim3(GT), 0, stream>>>(M2h, M2l, W2th, W2tl, b2,
                                           h2s, h2h, h2l);
  // K7: preds = h2 @ fcw + fcb
  fc_k<<<dim3(32), dim3(GT), 0, stream>>>(h2h, h2l, fwth, fwtl, fcb, out);
}